// Round 7
// baseline (120.616 us; speedup 1.0000x reference)
//
#include <hip/hip_runtime.h>
#include <hip/hip_bf16.h>

#define T_LEN 2048
#define NBATCH 32

typedef __bf16 bf16x8 __attribute__((ext_vector_type(8)));
typedef float f32x4 __attribute__((ext_vector_type(4)));
typedef float f32x16 __attribute__((ext_vector_type(16)));

__device__ __forceinline__ unsigned short f2bf(float f) {
  return __builtin_bit_cast(unsigned short, __float2bfloat16(f));
}
__device__ __forceinline__ unsigned int pk2(float a, float b) {
  return (unsigned int)f2bf(a) | ((unsigned int)f2bf(b) << 16);
}
__device__ __forceinline__ bf16x8 ld16(const void* p) {
  return __builtin_bit_cast(bf16x8, *(const uint4*)p);
}
// async global->LDS, 16B per lane: lds dest = uniform base + lane*16 (linear),
// global src is PER-LANE (pre-swizzled by caller).
__device__ __forceinline__ void gl_lds16(const void* g, void* l) {
  __builtin_amdgcn_global_load_lds(
      (const __attribute__((address_space(1))) unsigned int*)g,
      (__attribute__((address_space(3))) unsigned int*)l, 16, 0, 0);
}

// ---------------- Kernel 0: W -> Wt3 bf16 [192][384] (col-major over N) --------
__global__ __launch_bounds__(256) void k_wprep(const float* __restrict__ Wq,
                                               const float* __restrict__ Wk,
                                               const float* __restrict__ Wv,
                                               unsigned short* __restrict__ Wt3) {
  int idx = blockIdx.x * 256 + threadIdx.x;   // 0 .. 192*384-1
  if (idx >= 192 * 384) return;
  int c = idx / 384;          // output col 0..191
  int k = idx % 384;          // k dim
  const float* W = (c < 64) ? Wq : ((c < 128) ? Wk : Wv);
  Wt3[idx] = f2bf(W[k * 64 + (c & 63)]);
}

// ---------------- Kernel 1: QKV projection (MFMA bf16) -------------------------
// x fp32 [B*T][384] -> Q,K bf16 [B*T][64], VT bf16 [B][64][T]
__global__ __launch_bounds__(256) void k_proj(const float* __restrict__ x,
                                              const unsigned short* __restrict__ Wt3,
                                              unsigned short* __restrict__ Qb,
                                              unsigned short* __restrict__ Kb,
                                              unsigned short* __restrict__ VTb) {
  __shared__ __align__(16) unsigned short xs[128 * 32];   // swizzled
  __shared__ __align__(16) unsigned short wt[192 * 32];   // swizzled
  const int tid = threadIdx.x;
  const int lane = tid & 63, w = tid >> 6;
  const int g = lane >> 4, lr = lane & 15;
  const long row0 = (long)blockIdx.x * 128;

  f32x4 acc[2][12] = {};

  for (int ks = 0; ks < 12; ++ks) {
    const int k0 = ks * 32;
    __syncthreads();
    // stage x tile [128][32] fp32->bf16
    {
      int r = tid >> 1, c0 = (tid & 1) * 16;
      const float4* src = reinterpret_cast<const float4*>(&x[(row0 + r) * 384 + k0 + c0]);
      float4 f0 = src[0], f1 = src[1], f2 = src[2], f3 = src[3];
      uint4 u0, u1;
      u0.x = pk2(f0.x, f0.y); u0.y = pk2(f0.z, f0.w);
      u0.z = pk2(f1.x, f1.y); u0.w = pk2(f1.z, f1.w);
      u1.x = pk2(f2.x, f2.y); u1.y = pk2(f2.z, f2.w);
      u1.z = pk2(f3.x, f3.y); u1.w = pk2(f3.z, f3.w);
      int b0 = (r * 64 + c0 * 2) ^ ((r & 7) << 4);
      int b1 = (r * 64 + c0 * 2 + 16) ^ ((r & 7) << 4);
      *reinterpret_cast<uint4*>((char*)xs + b0) = u0;
      *reinterpret_cast<uint4*>((char*)xs + b1) = u1;
    }
    // stage Wt3 tile [192 cols][32 k]
#pragma unroll
    for (int j = 0; j < 3; ++j) {
      int chunk = tid + 256 * j;        // 0..767
      int r = chunk >> 2, c8 = chunk & 3;
      uint4 d = *reinterpret_cast<const uint4*>(&Wt3[r * 384 + k0 + c8 * 8]);
      int b = (r * 64 + c8 * 16) ^ ((r & 7) << 4);
      *reinterpret_cast<uint4*>((char*)wt + b) = d;
    }
    __syncthreads();

    bf16x8 a[2];
#pragma unroll
    for (int mt = 0; mt < 2; ++mt) {
      int r = w * 32 + mt * 16 + lr;
      a[mt] = ld16((char*)xs + ((r * 64 + g * 16) ^ ((r & 7) << 4)));
    }
#pragma unroll
    for (int n = 0; n < 12; ++n) {
      int r = n * 16 + lr;
      bf16x8 bb = ld16((char*)wt + ((r * 64 + g * 16) ^ ((r & 7) << 4)));
      acc[0][n] = __builtin_amdgcn_mfma_f32_16x16x32_bf16(a[0], bb, acc[0][n], 0, 0, 0);
      acc[1][n] = __builtin_amdgcn_mfma_f32_16x16x32_bf16(a[1], bb, acc[1][n], 0, 0, 0);
    }
  }

  // epilogue: D layout col = lr, row = g*4 + rr
#pragma unroll
  for (int mt = 0; mt < 2; ++mt)
#pragma unroll
    for (int n = 0; n < 12; ++n)
#pragma unroll
      for (int rr = 0; rr < 4; ++rr) {
        long grow = row0 + w * 32 + mt * 16 + g * 4 + rr;
        int col = n * 16 + lr;
        unsigned short hv = f2bf(acc[mt][n][rr]);
        if (n < 4) {
          Qb[grow * 64 + col] = hv;
        } else if (n < 8) {
          Kb[grow * 64 + (col - 64)] = hv;
        } else {
          long bb_ = grow >> 11;          // / 2048
          long t = grow & 2047;
          VTb[(bb_ * 64 + (col - 128)) * 2048 + t] = hv;
        }
      }
}

// ---------------- Kernel 2: causal flash attention, swapped-QK 32x32 (T12) -----
// ROUND-7 RESTRUCTURE: 2-wave (128-thread) blocks of 64 q-rows -> grid 1024
// (was 512 4-wave blocks: exactly-2-dispatch-rounds with qb+1 cost imbalance
// left ~1 block/CU resident = 1 wave/SIMD, zero TLP, 12.5% occupancy).
// Wave structure unchanged: lane owns ONE q-row via S^T = mfma(K,Q); lane-local
// defer-max softmax; P repacked to PV A-fragments in registers (shfl_xor(32));
// K/V double-buffered in LDS via global_load_lds w/ pre-swizzled source.
__global__ __launch_bounds__(128, 2) void k_attn(const unsigned short* __restrict__ Qb,
                                                 const unsigned short* __restrict__ Kb,
                                                 const unsigned short* __restrict__ VTb,
                                                 float* __restrict__ out) {
  __shared__ __align__(16) char ksm[2 * 8192];   // K tiles [64 kv][64 hs]
  __shared__ __align__(16) char vsm[2 * 8192];   // V^T tiles [64 d][64 kv]

  const int tid = threadIdx.x;
  const int lane = tid & 63, w = tid >> 6;       // w in {0,1}
  const int h = lane >> 5, q31 = lane & 31;
  const int b = blockIdx.x;
  const int qb = (gridDim.y - 1) - blockIdx.y;   // longest-first dispatch
  const int qw = qb * 64 + w * 32;               // wave's first q row
  const int qrow = qw + q31;                     // lane's S q-row

  const char* Kg = (const char*)(Kb + (long)b * T_LEN * 64);   // row stride 128 B
  const char* Vg = (const char*)(VTb + (long)b * 64 * 2048);   // row stride 4096 B

  const int lrow = lane >> 3;                    // 0..7
  const int lsw = (((lane & 7) ^ lrow) << 4);    // pre-swizzled source col

  // Q B-fragments: lane holds Q[qrow][c*16 + h*8 + i], i=0..7
  bf16x8 qf[4];
#pragma unroll
  for (int c = 0; c < 4; ++c)
    qf[c] = ld16(&Qb[(long)(b * T_LEN + qrow) * 64 + c * 16 + h * 8]);

  f32x16 o[2] = {};            // O[q(reg-mapped)][d = db*32 + q31]
  float m_r = -1e30f, l_r = 0.f;

  const int nkv = qb + 1;

  // ---- prologue: stage tile 0 into buffer 0 (each wave: 32 K-rows + 32 V-rows)
#pragma unroll
  for (int sub = 0; sub < 4; ++sub) {
    int r = w * 32 + sub * 8 + lrow;
    gl_lds16(Kg + (long)r * 128 + lsw, ksm + w * 4096 + sub * 1024);
    gl_lds16(Vg + (long)r * 4096 + lsw, vsm + w * 4096 + sub * 1024);
  }
  __syncthreads();

  int cur = 0;
  for (int t = 0; t < nkv; ++t) {
    const int kv0 = t * 64;

    // ---- issue next tile's stage into the other buffer
    if (t + 1 < nkv) {
      const int kv1 = kv0 + 64;
      char* kb = ksm + (cur ^ 1) * 8192 + w * 4096;
      char* vb = vsm + (cur ^ 1) * 8192 + w * 4096;
#pragma unroll
      for (int sub = 0; sub < 4; ++sub) {
        int r = w * 32 + sub * 8 + lrow;
        gl_lds16(Kg + (long)(kv1 + r) * 128 + lsw, kb + sub * 1024);
        gl_lds16(Vg + (long)r * 4096 + (long)kv1 * 2 + lsw, vb + sub * 1024);
      }
    }

    char* kt = ksm + cur * 8192;
    char* vt = vsm + cur * 8192;

    if (kv0 <= qw + 31) {        // wave-uniform: skip fully-masked tiles
      // ---- S^T = K Q^T : lane owns q-col = q31; 32 kv rows per mf-half
      f32x16 s[2] = {};
      __builtin_amdgcn_s_setprio(1);
#pragma unroll
      for (int mf = 0; mf < 2; ++mf)
#pragma unroll
        for (int c = 0; c < 4; ++c) {
          int r = mf * 32 + q31;
          bf16x8 kf = ld16(kt + r * 128 + ((c * 32 + h * 16) ^ ((r & 7) << 4)));
          s[mf] = __builtin_amdgcn_mfma_f32_32x32x16_bf16(kf, qf[c], s[mf], 0, 0, 0);
        }
      __builtin_amdgcn_s_setprio(0);

      // ---- scale + causal mask (tile needs mask iff it can exceed qw)
      const bool domask = (kv0 + 63 > qw);
#pragma unroll
      for (int mf = 0; mf < 2; ++mf)
#pragma unroll
        for (int r = 0; r < 16; ++r) {
          float v = s[mf][r] * 0.125f;
          if (domask) {
            int kvv = kv0 + mf * 32 + (r & 3) + 8 * (r >> 2) + 4 * h;
            if (kvv > qrow) v = -1e30f;
          }
          s[mf][r] = v;
        }

      // ---- T13 defer-max softmax (lane-local; partner exchange only on rescale)
      float pm = -3e38f;
#pragma unroll
      for (int mf = 0; mf < 2; ++mf)
#pragma unroll
        for (int r = 0; r < 16; ++r) pm = fmaxf(pm, s[mf][r]);
      if (__any(pm > m_r + 8.0f)) {
        float mx = fmaxf(pm, __shfl_xor(pm, 32));   // full-row max (both halves)
        float mn = fmaxf(m_r, mx);
        float sc = exp2f((m_r - mn) * 1.44269504f);
        m_r = mn;
        l_r *= sc;
#pragma unroll
        for (int r = 0; r < 16; ++r) {
          int qp = (r & 3) + 8 * (r >> 2) + 4 * h;   // o-row's q index
          float scq = __shfl(sc, qp);
          o[0][r] *= scq;
          o[1][r] *= scq;
        }
      }
#pragma unroll
      for (int mf = 0; mf < 2; ++mf)
#pragma unroll
        for (int r = 0; r < 16; ++r) {
          float p = exp2f((s[mf][r] - m_r) * 1.44269504f);
          s[mf][r] = p;
          l_r += p;
        }

      // ---- P->A-fragment in registers + PV
      __builtin_amdgcn_s_setprio(1);
#pragma unroll
      for (int c = 0; c < 4; ++c) {
        const int mf = c >> 1, rb = (c & 1) * 8;
        unsigned int lo0 = pk2(s[mf][rb + 0], s[mf][rb + 1]);
        unsigned int lo1 = pk2(s[mf][rb + 2], s[mf][rb + 3]);
        unsigned int hi0 = pk2(s[mf][rb + 4], s[mf][rb + 5]);
        unsigned int hi1 = pk2(s[mf][rb + 6], s[mf][rb + 7]);
        // partner exchange: h=0 needs partner's lo (kv +4..7), h=1 needs partner's hi
        unsigned int sA = h ? lo0 : hi0;
        unsigned int sB = h ? lo1 : hi1;
        unsigned int rA = (unsigned int)__shfl_xor((int)sA, 32);
        unsigned int rB = (unsigned int)__shfl_xor((int)sB, 32);
        uint4 pw;
        pw.x = h ? rA : lo0;
        pw.y = h ? rB : lo1;
        pw.z = h ? hi0 : rA;
        pw.w = h ? hi1 : rB;
        bf16x8 pf = __builtin_bit_cast(bf16x8, pw);
#pragma unroll
        for (int db = 0; db < 2; ++db) {
          int rd = db * 32 + q31;
          bf16x8 vf = ld16(vt + rd * 128 + ((c * 32 + h * 16) ^ ((rd & 7) << 4)));
          o[db] = __builtin_amdgcn_mfma_f32_32x32x16_bf16(pf, vf, o[db], 0, 0, 0);
        }
      }
      __builtin_amdgcn_s_setprio(0);
    }

    __syncthreads();   // drains vmcnt: stage(t+1) complete; all waves done reading
    cur ^= 1;
  }

  // ---- epilogue: combine partner l, scale rows, store
  float lt = l_r + __shfl_xor(l_r, 32);
  float linv = 1.0f / lt;
#pragma unroll
  for (int r = 0; r < 16; ++r) {
    int qp = (r & 3) + 8 * (r >> 2) + 4 * h;
    float iv = __shfl(linv, qp);
    long rowg = (long)(b * T_LEN + qw + qp);
    out[rowg * 64 + q31]      = o[0][r] * iv;
    out[rowg * 64 + 32 + q31] = o[1][r] * iv;
  }
}

// ---------------- launch -------------------------------------------------------
extern "C" void kernel_launch(void* const* d_in, const int* in_sizes, int n_in,
                              void* d_out, int out_size, void* d_ws, size_t ws_size,
                              hipStream_t stream) {
  const float* x  = (const float*)d_in[0];
  const float* Wq = (const float*)d_in[1];
  const float* Wk = (const float*)d_in[2];
  const float* Wv = (const float*)d_in[3];
  float* out = (float*)d_out;

  char* ws = (char*)d_ws;
  unsigned short* Wt3 = (unsigned short*)ws;                          // 294912 B
  unsigned short* Qb  = (unsigned short*)(ws + 0x80000);              // 8 MiB each
  unsigned short* Kb  = (unsigned short*)(ws + 0x80000 + 0x800000);
  unsigned short* VTb = (unsigned short*)(ws + 0x80000 + 0x1000000);

  k_wprep<<<dim3(288), dim3(256), 0, stream>>>(Wq, Wk, Wv, Wt3);
  k_proj<<<dim3(512), dim3(256), 0, stream>>>(x, Wt3, Qb, Kb, VTb);
  // grid: x = batch (fast), y = 64-row q-block reversed -> heaviest first
  k_attn<<<dim3(NBATCH, 32), dim3(128), 0, stream>>>(Qb, Kb, VTb, out);
}

// Round 8
// 87.376 us; speedup vs baseline: 1.3804x; 1.3804x over previous
//
#include <hip/hip_runtime.h>
#include <hip/hip_bf16.h>

#define T_LEN 2048
#define NBATCH 32

typedef __bf16 bf16x8 __attribute__((ext_vector_type(8)));
typedef float f32x4 __attribute__((ext_vector_type(4)));

__device__ __forceinline__ unsigned short f2bf(float f) {
  return __builtin_bit_cast(unsigned short, __float2bfloat16(f));
}
__device__ __forceinline__ unsigned int pk2(float a, float b) {
  return (unsigned int)f2bf(a) | ((unsigned int)f2bf(b) << 16);
}
__device__ __forceinline__ bf16x8 ld16(const void* p) {
  return __builtin_bit_cast(bf16x8, *(const uint4*)p);
}
// async global->LDS, 16B per lane: lds dest = uniform base + lane*16 (linear),
// global src is PER-LANE (pre-swizzled by caller).
__device__ __forceinline__ void gl_lds16(const void* g, void* l) {
  __builtin_amdgcn_global_load_lds(
      (const __attribute__((address_space(1))) unsigned int*)g,
      (__attribute__((address_space(3))) unsigned int*)l, 16, 0, 0);
}
// raw barrier WITHOUT the vmcnt(0) drain __syncthreads() implies.
__device__ __forceinline__ void bar_raw() {
  asm volatile("s_barrier" ::: "memory");
}

// ---------------- Kernel 0: W -> Wt3 bf16 [192][384] (col-major over N) --------
__global__ __launch_bounds__(256) void k_wprep(const float* __restrict__ Wq,
                                               const float* __restrict__ Wk,
                                               const float* __restrict__ Wv,
                                               unsigned short* __restrict__ Wt3) {
  int idx = blockIdx.x * 256 + threadIdx.x;   // 0 .. 192*384-1
  if (idx >= 192 * 384) return;
  int c = idx / 384;          // output col 0..191
  int k = idx % 384;          // k dim
  const float* W = (c < 64) ? Wq : ((c < 128) ? Wk : Wv);
  Wt3[idx] = f2bf(W[k * 64 + (c & 63)]);
}

// ---------------- Kernel 1: QKV projection (MFMA bf16) -------------------------
// x fp32 [B*T][384] -> Q,K bf16 [B*T][64], VT bf16 [B][64][T]
__global__ __launch_bounds__(256) void k_proj(const float* __restrict__ x,
                                              const unsigned short* __restrict__ Wt3,
                                              unsigned short* __restrict__ Qb,
                                              unsigned short* __restrict__ Kb,
                                              unsigned short* __restrict__ VTb) {
  __shared__ __align__(16) unsigned short xs[128 * 32];   // swizzled
  __shared__ __align__(16) unsigned short wt[192 * 32];   // swizzled
  const int tid = threadIdx.x;
  const int lane = tid & 63, w = tid >> 6;
  const int g = lane >> 4, lr = lane & 15;
  const long row0 = (long)blockIdx.x * 128;

  f32x4 acc[2][12] = {};

  for (int ks = 0; ks < 12; ++ks) {
    const int k0 = ks * 32;
    __syncthreads();
    // stage x tile [128][32] fp32->bf16
    {
      int r = tid >> 1, c0 = (tid & 1) * 16;
      const float4* src = reinterpret_cast<const float4*>(&x[(row0 + r) * 384 + k0 + c0]);
      float4 f0 = src[0], f1 = src[1], f2 = src[2], f3 = src[3];
      uint4 u0, u1;
      u0.x = pk2(f0.x, f0.y); u0.y = pk2(f0.z, f0.w);
      u0.z = pk2(f1.x, f1.y); u0.w = pk2(f1.z, f1.w);
      u1.x = pk2(f2.x, f2.y); u1.y = pk2(f2.z, f2.w);
      u1.z = pk2(f3.x, f3.y); u1.w = pk2(f3.z, f3.w);
      int b0 = (r * 64 + c0 * 2) ^ ((r & 7) << 4);
      int b1 = (r * 64 + c0 * 2 + 16) ^ ((r & 7) << 4);
      *reinterpret_cast<uint4*>((char*)xs + b0) = u0;
      *reinterpret_cast<uint4*>((char*)xs + b1) = u1;
    }
    // stage Wt3 tile [192 cols][32 k]
#pragma unroll
    for (int j = 0; j < 3; ++j) {
      int chunk = tid + 256 * j;        // 0..767
      int r = chunk >> 2, c8 = chunk & 3;
      uint4 d = *reinterpret_cast<const uint4*>(&Wt3[r * 384 + k0 + c8 * 8]);
      int b = (r * 64 + c8 * 16) ^ ((r & 7) << 4);
      *reinterpret_cast<uint4*>((char*)wt + b) = d;
    }
    __syncthreads();

    bf16x8 a[2];
#pragma unroll
    for (int mt = 0; mt < 2; ++mt) {
      int r = w * 32 + mt * 16 + lr;
      a[mt] = ld16((char*)xs + ((r * 64 + g * 16) ^ ((r & 7) << 4)));
    }
#pragma unroll
    for (int n = 0; n < 12; ++n) {
      int r = n * 16 + lr;
      bf16x8 bb = ld16((char*)wt + ((r * 64 + g * 16) ^ ((r & 7) << 4)));
      acc[0][n] = __builtin_amdgcn_mfma_f32_16x16x32_bf16(a[0], bb, acc[0][n], 0, 0, 0);
      acc[1][n] = __builtin_amdgcn_mfma_f32_16x16x32_bf16(a[1], bb, acc[1][n], 0, 0, 0);
    }
  }

  // epilogue: D layout col = lr, row = g*4 + rr
#pragma unroll
  for (int mt = 0; mt < 2; ++mt)
#pragma unroll
    for (int n = 0; n < 12; ++n)
#pragma unroll
      for (int rr = 0; rr < 4; ++rr) {
        long grow = row0 + w * 32 + mt * 16 + g * 4 + rr;
        int col = n * 16 + lr;
        unsigned short hv = f2bf(acc[mt][n][rr]);
        if (n < 4) {
          Qb[grow * 64 + col] = hv;
        } else if (n < 8) {
          Kb[grow * 64 + (col - 64)] = hv;
        } else {
          long bb_ = grow >> 11;          // / 2048
          long t = grow & 2047;
          VTb[(bb_ * 64 + (col - 128)) * 2048 + t] = hv;
        }
      }
}

// ---------------- Kernel 2: causal flash attention ------------------------------
// ROUND-8: back to the R4 structure (16x16, 4 waves x 16 q-rows, P via per-wave
// LDS, defer-max softmax, per-lane l partials) -- it beat the 32x32 swap by
// ~1.7x thanks to 2x the wave-level TLP. New: T4 counted-vmcnt pipeline.
// __syncthreads() (which drains vmcnt(0) = the just-issued stage!) is replaced
// by raw barriers + s_waitcnt vmcnt(4):
//   barrierA: all waves done READING buf[cur^1] -> safe to overwrite
//   stage(t+1) -> buf[cur^1]           [4 gl_lds16 per wave]
//   vmcnt(4): our stage(t) landed; barrierB: everyone's stage(t) landed
//   compute on buf[cur]                [no drain of stage(t+1)!]
// Cross-wave safety: each wave waits vmcnt(4) BEFORE barrierB, so after
// barrierB all waves' stage(t) LDS writes are visible (m201 mechanism).
__global__ __launch_bounds__(256, 4) void k_attn(const unsigned short* __restrict__ Qb,
                                                 const unsigned short* __restrict__ Kb,
                                                 const unsigned short* __restrict__ VTb,
                                                 float* __restrict__ out) {
  __shared__ __align__(16) char ksm[2 * 8192];              // K tiles [64][64]
  __shared__ __align__(16) char vsm[2 * 8192];              // V^T tiles [64][64]
  __shared__ __align__(16) unsigned short psm[4 * 16 * 64]; // per-wave P, swizzled

  const int tid = threadIdx.x;
  const int lane = tid & 63, w = tid >> 6;
  const int g = lane >> 4, lr = lane & 15;
  const int b = blockIdx.x;
  const int qt = (gridDim.y - 1) - blockIdx.y;   // longest-first dispatch
  const int qrow0 = qt * 64 + w * 16;

  const char* Kg = (const char*)(Kb + (long)b * T_LEN * 64);   // row stride 128 B
  const char* Vg = (const char*)(VTb + (long)b * 64 * 2048);   // row stride 4096 B

  // staging: lane writes LDS bytes [16*lane..) of its wave's 2048-B segment;
  // source byte within row pre-swizzled so swizzled ds_read_b128 reads match.
  const int lrow = lane >> 3;
  const int lsw = (((lane & 7) ^ lrow) << 4);

  // Q fragments (A operand): lane holds Q[qrow0+lr][c*32 + g*8 + i]
  bf16x8 qf[2];
#pragma unroll
  for (int c = 0; c < 2; ++c)
    qf[c] = ld16(&Qb[((long)(b * T_LEN + qrow0 + lr)) * 64 + c * 32 + g * 8]);

  f32x4 o[4] = {};
  float m_r[4], l_r[4];   // l_r: PER-LANE partial sums (reduced at epilogue)
#pragma unroll
  for (int r = 0; r < 4; ++r) { m_r[r] = -1e30f; l_r[r] = 0.f; }

  char* pbase = (char*)psm + w * 2048;
  const int nkv = qt + 1;

  // ---- prologue: stage tile 0 into buffer 0 (4 loads/wave; completion gated
  // by iter-0's vmcnt(4)+barrierB)
  {
    const char* gk = Kg + ((long)(w * 16 + lrow)) * 128 + lsw;
    const char* gv = Vg + ((long)(w * 16 + lrow)) * 4096 + lsw;
    char* kb = ksm + w * 2048;
    char* vb = vsm + w * 2048;
    gl_lds16(gk, kb);             gl_lds16(gk + 8 * 128, kb + 1024);
    gl_lds16(gv, vb);             gl_lds16(gv + 8 * 4096, vb + 1024);
  }

  int cur = 0;
  for (int t = 0; t < nkv; ++t) {
    const int kv0 = t * 64;

    // ---- barrier A: all waves finished reading buf[cur^1] (iter t-1)
    bar_raw();

    // ---- stage(t+1) into buf[cur^1]; then gate on stage(t) completion
    if (t + 1 < nkv) {
      const int kv1 = kv0 + 64;
      const char* gk = Kg + ((long)(kv1 + w * 16 + lrow)) * 128 + lsw;
      const char* gv = Vg + ((long)(w * 16 + lrow)) * 4096 + (long)kv1 * 2 + lsw;
      char* kb = ksm + (cur ^ 1) * 8192 + w * 2048;
      char* vb = vsm + (cur ^ 1) * 8192 + w * 2048;
      gl_lds16(gk, kb);           gl_lds16(gk + 8 * 128, kb + 1024);
      gl_lds16(gv, vb);           gl_lds16(gv + 8 * 4096, vb + 1024);
      asm volatile("s_waitcnt vmcnt(4)" ::: "memory");   // stage(t) done, t+1 in flight
    } else {
      asm volatile("s_waitcnt vmcnt(0)" ::: "memory");   // last tile: drain all
    }
    bar_raw();   // barrier B: every wave's stage(t) landed in LDS

    char* kt = ksm + cur * 8192;
    char* vt = vsm + cur * 8192;

    // ---- S = Q K^T (K from LDS, swizzled reads)
    f32x4 s[4] = {};
    __builtin_amdgcn_s_setprio(1);
#pragma unroll
    for (int c = 0; c < 2; ++c)
#pragma unroll
      for (int n = 0; n < 4; ++n) {
        int r = n * 16 + lr;
        bf16x8 kf = ld16(kt + ((r * 128 + c * 64 + g * 16) ^ ((r & 7) << 4)));
        s[n] = __builtin_amdgcn_mfma_f32_16x16x32_bf16(qf[c], kf, s[n], 0, 0, 0);
      }
    __builtin_amdgcn_s_setprio(0);

    // ---- scale + causal mask (only diagonal tile)
    const bool diag = (t == qt);
#pragma unroll
    for (int n = 0; n < 4; ++n)
#pragma unroll
      for (int r = 0; r < 4; ++r) {
        float v = s[n][r] * 0.125f;
        if (diag) {
          int col = kv0 + n * 16 + lr;
          int rowq = qrow0 + g * 4 + r;
          if (col > rowq) v = -1e30f;
        }
        s[n][r] = v;
      }

    // ---- T13 defer-max online softmax
    float pm[4];
#pragma unroll
    for (int r = 0; r < 4; ++r)
      pm[r] = fmaxf(fmaxf(s[0][r], s[1][r]), fmaxf(s[2][r], s[3][r]));
    bool need = false;
#pragma unroll
    for (int r = 0; r < 4; ++r) need = need || (pm[r] > m_r[r] + 8.0f);
    if (__any((int)need)) {
#pragma unroll
      for (int r = 0; r < 4; ++r) {
        float mx = pm[r];
        mx = fmaxf(mx, __shfl_xor(mx, 1));
        mx = fmaxf(mx, __shfl_xor(mx, 2));
        mx = fmaxf(mx, __shfl_xor(mx, 4));
        mx = fmaxf(mx, __shfl_xor(mx, 8));
        float mn = fmaxf(m_r[r], mx);
        float sc = exp2f((m_r[r] - mn) * 1.44269504f);
        m_r[r] = mn;
        l_r[r] *= sc;
#pragma unroll
        for (int n = 0; n < 4; ++n) o[n][r] *= sc;
      }
    }
    float pr[4][4];
#pragma unroll
    for (int r = 0; r < 4; ++r)
#pragma unroll
      for (int n = 0; n < 4; ++n) {
        float p = exp2f((s[n][r] - m_r[r]) * 1.44269504f);
        pr[n][r] = p;
        l_r[r] += p;                    // per-lane partial; no shfl here
      }

    // ---- P -> LDS (per-wave buffer; wave-internal write->read, no barrier)
#pragma unroll
    for (int n = 0; n < 4; ++n)
#pragma unroll
      for (int r = 0; r < 4; ++r) {
        int rq = g * 4 + r;
        int col = n * 16 + lr;
        *(unsigned short*)(pbase + ((rq * 128 + col * 2) ^ ((rq & 7) << 4))) = f2bf(pr[n][r]);
      }

    // ---- O += P V (V from LDS)
    bf16x8 pf[2];
#pragma unroll
    for (int c = 0; c < 2; ++c)
      pf[c] = ld16(pbase + ((lr * 128 + c * 64 + g * 16) ^ ((lr & 7) << 4)));
    __builtin_amdgcn_s_setprio(1);
#pragma unroll
    for (int c = 0; c < 2; ++c)
#pragma unroll
      for (int n = 0; n < 4; ++n) {
        int r = n * 16 + lr;
        bf16x8 vf = ld16(vt + ((r * 128 + c * 64 + g * 16) ^ ((r & 7) << 4)));
        o[n] = __builtin_amdgcn_mfma_f32_16x16x32_bf16(pf[c], vf, o[n], 0, 0, 0);
      }
    __builtin_amdgcn_s_setprio(0);

    cur ^= 1;
  }

  // epilogue: reduce l across the 16 lanes of the group (once), then scale+store
#pragma unroll
  for (int r = 0; r < 4; ++r) {
    float l = l_r[r];
    l += __shfl_xor(l, 1);
    l += __shfl_xor(l, 2);
    l += __shfl_xor(l, 4);
    l += __shfl_xor(l, 8);
    float inv = 1.0f / l;
#pragma unroll
    for (int n = 0; n < 4; ++n) {
      long rowg = (long)b * T_LEN + qrow0 + g * 4 + r;
      out[rowg * 64 + n * 16 + lr] = o[n][r] * inv;
    }
  }
}

// ---------------- launch -------------------------------------------------------
extern "C" void kernel_launch(void* const* d_in, const int* in_sizes, int n_in,
                              void* d_out, int out_size, void* d_ws, size_t ws_size,
                              hipStream_t stream) {
  const float* x  = (const float*)d_in[0];
  const float* Wq = (const float*)d_in[1];
  const float* Wk = (const float*)d_in[2];
  const float* Wv = (const float*)d_in[3];
  float* out = (float*)d_out;

  char* ws = (char*)d_ws;
  unsigned short* Wt3 = (unsigned short*)ws;                          // 294912 B
  unsigned short* Qb  = (unsigned short*)(ws + 0x80000);              // 8 MiB each
  unsigned short* Kb  = (unsigned short*)(ws + 0x80000 + 0x800000);
  unsigned short* VTb = (unsigned short*)(ws + 0x80000 + 0x1000000);

  k_wprep<<<dim3(288), dim3(256), 0, stream>>>(Wq, Wk, Wv, Wt3);
  k_proj<<<dim3(512), dim3(256), 0, stream>>>(x, Wt3, Qb, Kb, VTb);
  // grid: x = batch (fast), y = q-tile reversed -> heaviest q-tiles dispatch first
  k_attn<<<dim3(NBATCH, 32), dim3(256), 0, stream>>>(Qb, Kb, VTb, out);
}